// Round 3
// baseline (93.719 us; speedup 1.0000x reference)
//
#include <hip/hip_runtime.h>
#include <hip/hip_bf16.h>

// out[b, 2t+r, c*128+d] = normed outer product of x[b,t,:] with itself.
// ||flatten(w*x⊗x)||_2 = |w| * (Σ x_c^2)  => per-frame: 128-elem sum of squares
// + rank-1 outer product streamed twice (UpSampling1D repeat).
// Pure HBM-write-bound: 512 MiB writes, 2 MiB reads.
//
// Round 3: plain streaming stores (fillBufferAligned hits 6.65 TB/s with plain
// stores; testing whether the `nt` flag was costing ~13% steady-state BW),
// and single-barrier prologue.

#define C 128
#define CC (C * C)       // 16384
#define CC4 (CC / 4)     // 4096 float4 per time-row
#define NTHREADS 256
#define EPS 1e-12f

typedef float f32x4 __attribute__((ext_vector_type(4)));

__global__ __launch_bounds__(NTHREADS) void frame_outer_kernel(
    const float* __restrict__ x,   // (BT, 128)
    const float* __restrict__ w,   // (1,)
    float* __restrict__ out)       // (BT*2, 16384)
{
    __shared__ __align__(16) float xs[C];   // x row
    __shared__ float partials[4];

    const int frame = blockIdx.x;
    const int tid = threadIdx.x;
    const float* __restrict__ xrow = x + (size_t)frame * C;

    // Load x row (threads 0..127), write to LDS, wave-reduce sum of squares.
    float v = 0.0f;
    if (tid < C) {
        v = xrow[tid];
        xs[tid] = v;
    }
    float p = v * v;
    #pragma unroll
    for (int off = 32; off > 0; off >>= 1)
        p += __shfl_down(p, off);
    if ((tid & 63) == 0) partials[tid >> 6] = p;
    __syncthreads();   // single barrier: xs[] and partials[] both ready

    const float S = partials[0] + partials[1] + partials[2] + partials[3];
    const float wv = w[0];
    const float ws = wv * S;
    const float rs = rsqrtf(fmaxf(ws * ws, EPS));
    const float wrs = wv * rs;

    // out[c*128+d] = (wv*rs*xs[c]) * xs[d], to rows 2t and 2t+1.
    const f32x4* __restrict__ x4 = (const f32x4*)xs;
    float* __restrict__ obase = out + (size_t)frame * 2 * CC;
    f32x4* __restrict__ o0 = (f32x4*)obase;
    f32x4* __restrict__ o1 = (f32x4*)(obase + CC);

    const int d4 = tid & 31;              // float4 col — loop-invariant per thread
    const f32x4 xv = x4[d4];
    #pragma unroll
    for (int k = 0; k < CC4 / NTHREADS; ++k) {      // 16 iterations
        const int i = k * NTHREADS + tid;           // float4 index in row
        const int c = i >> 5;                       // outer-product row
        const float a = wrs * xs[c];
        f32x4 r = a * xv;
        o0[i] = r;
        o1[i] = r;
    }
}

extern "C" void kernel_launch(void* const* d_in, const int* in_sizes, int n_in,
                              void* d_out, int out_size, void* d_ws, size_t ws_size,
                              hipStream_t stream) {
    const float* x = (const float*)d_in[0];
    const float* w = (const float*)d_in[1];
    float* out = (float*)d_out;

    const int BT = in_sizes[0] / C;  // 8 * 512 = 4096 frames
    frame_outer_kernel<<<BT, NTHREADS, 0, stream>>>(x, w, out);
}

// Round 4
// 91.592 us; speedup vs baseline: 1.0232x; 1.0232x over previous
//
#include <hip/hip_runtime.h>
#include <hip/hip_bf16.h>

// out[b, 2t+r, c*128+d] = normed outer product of x[b,t,:] with itself.
// ||flatten(w*x⊗x)||_2 = |w| * (Σ x_c^2)  => per-frame: 128-elem sum of squares
// + rank-1 outer product streamed twice (UpSampling1D repeat).
// Pure HBM-write-bound: 512 MiB writes, 2 MiB reads.
//
// Round 4: 4 frames per block (1024 blocks = 4/CU exactly) to amortize the
// prologue (row load + reduce + barrier) over 4x the store work.

#define C 128
#define CC (C * C)       // 16384
#define CC4 (CC / 4)     // 4096 float4 per time-row
#define NTHREADS 256
#define FPB 4            // frames per block
#define EPS 1e-12f

typedef float f32x4 __attribute__((ext_vector_type(4)));

__global__ __launch_bounds__(NTHREADS) void frame_outer_kernel(
    const float* __restrict__ x,   // (BT, 128)
    const float* __restrict__ w,   // (1,)
    float* __restrict__ out)       // (BT*2, 16384)
{
    __shared__ __align__(16) float xs[FPB][C];
    __shared__ float par[8];   // per-wave partial sums: [0..3] rows 0-1, [4..7] rows 2-3

    const int tid = threadIdx.x;
    const int frame0 = blockIdx.x * FPB;
    const float* __restrict__ xr = x + (size_t)frame0 * C;

    // Load 4 rows (512 floats) with 256 threads, 2 elements each.
    const float v0 = xr[tid];          // covers rows 0-1
    const float v1 = xr[tid + 256];    // covers rows 2-3
    ((float*)xs)[tid]       = v0;
    ((float*)xs)[tid + 256] = v1;

    // Each wave (64 lanes) lies entirely within one row half: waves 0,1 -> row0;
    // 2,3 -> row1 (for v0); same +2 rows for v1. Reduce both in lockstep.
    float p0 = v0 * v0;
    float p1 = v1 * v1;
    #pragma unroll
    for (int off = 32; off > 0; off >>= 1) {
        p0 += __shfl_down(p0, off);
        p1 += __shfl_down(p1, off);
    }
    const int wid = tid >> 6;
    if ((tid & 63) == 0) {
        par[wid]     = p0;
        par[wid + 4] = p1;
    }
    __syncthreads();   // xs[] and par[] ready

    const float wv = w[0];
    float wrs[FPB];
    #pragma unroll
    for (int fi = 0; fi < FPB; ++fi) {
        const float S = par[2 * fi] + par[2 * fi + 1];
        const float ws = wv * S;
        wrs[fi] = wv * rsqrtf(fmaxf(ws * ws, EPS));
    }

    // Stream stores: for each frame, out[c*128+d] = (wrs*xs[c]) * xs[d],
    // written to time rows 2t and 2t+1.
    const int d4 = tid & 31;   // float4 column — fixed per thread
    #pragma unroll
    for (int fi = 0; fi < FPB; ++fi) {
        const f32x4 xv = ((const f32x4*)xs[fi])[d4];
        const float a0 = wrs[fi];
        float* __restrict__ obase = out + (size_t)(frame0 + fi) * 2 * CC;
        f32x4* __restrict__ o0 = (f32x4*)obase;
        f32x4* __restrict__ o1 = (f32x4*)(obase + CC);
        #pragma unroll
        for (int k = 0; k < CC4 / NTHREADS; ++k) {   // 16 iterations
            const int i = k * NTHREADS + tid;
            const int c = i >> 5;                    // broadcast LDS read (2 addrs/wave)
            const float a = a0 * xs[fi][c];
            f32x4 r = a * xv;
            o0[i] = r;
            o1[i] = r;
        }
    }
}

extern "C" void kernel_launch(void* const* d_in, const int* in_sizes, int n_in,
                              void* d_out, int out_size, void* d_ws, size_t ws_size,
                              hipStream_t stream) {
    const float* x = (const float*)d_in[0];
    const float* w = (const float*)d_in[1];
    float* out = (float*)d_out;

    const int BT = in_sizes[0] / C;          // 4096 frames
    const int nblocks = BT / FPB;            // 1024 blocks = 4 per CU
    frame_outer_kernel<<<nblocks, NTHREADS, 0, stream>>>(x, w, out);
}